// Round 9
// baseline (44.294 us; speedup 1.0000x reference)
//
#include <hip/hip_runtime.h>

// PCEN over x[B=64, M=128, T=4000] fp32, T contiguous.
// n_t = A*n_{t-1} + x_t (n = m/S) ; pcen = sqrt(x*(S*n+eps)^-0.98 + 2) - sqrt(2)
//
// R9: 4 waves per row. Each wave owns 4 batches of 256 timesteps (lane l owns
// [4l,4l+4) within a batch; every load/store is a fully-packed 1KB wave
// transaction). Waves seg>0 rebuild their incoming EMA state with ONE warmup
// batch (A^256 ~ 1.5e-3 -> output error ~4e-4, threshold 9.7e-2).
// All-DPP weighted inclusive scan; NT stores keep output out of L3.

#define TT     4000
#define NROWS  8192   // 64*128
#define SEGS   4      // waves per row
#define ITERS  4      // main batches per wave (SEGS*ITERS = 16)
#define NFULL  15     // batch 15 is the 160-elem tail
#define TAILL  40

typedef float f32x4 __attribute__((ext_vector_type(4)));

// dpp_ctrl (gfx9): row_shr:N = 0x110|N, row_bcast15=0x142, row_bcast31=0x143
#define DPPF(x, ctrl, rmask) \
    __int_as_float(__builtin_amdgcn_update_dpp(0, __float_as_int(x), (ctrl), (rmask), 0xf, false))

__global__ __launch_bounds__(256, 8) void pcen_kernel(const float* __restrict__ x,
                                                      float* __restrict__ out) {
    const int gwid = (blockIdx.x * blockDim.x + threadIdx.x) >> 6;
    const int lane = threadIdx.x & 63;
    const int row  = gwid >> 2;        // gwid / SEGS
    const int seg  = gwid & (SEGS - 1);
    const int base = seg * ITERS;

    const float S = 0.025f, A = 0.975f, EPS = 1e-6f, NA = -0.98f;
    const float SQRT2 = 1.41421356237f;

    const float A2   = A * A;
    const float A4   = A2 * A2;
    const float A8   = A4 * A4;
    const float A16  = A8 * A8;
    const float A32  = A16 * A16;
    const float A64  = A32 * A32;
    const float A128 = A64 * A64;
    const float A256 = A128 * A128;
    const float INVA4 = 1.0f / A4;

    // powAl = A^(4*lane)
    float powAl = 1.0f;
    if (lane & 1)  powAl *= A4;
    if (lane & 2)  powAl *= A8;
    if (lane & 4)  powAl *= A16;
    if (lane & 8)  powAl *= A32;
    if (lane & 16) powAl *= A64;
    if (lane & 32) powAl *= A128;

    // Per-lane weights for the DPP row-bcast combine steps.
    float p15 = 1.0f;
    if (lane & 1) p15 *= A4;
    if (lane & 2) p15 *= A8;
    if (lane & 4) p15 *= A16;
    if (lane & 8) p15 *= A32;
    float w15 = A4 * p15;                         // A^(4*((lane&15)+1))
    float w31 = (lane & 16) ? (w15 * A64) : w15;  // A^(4*((lane&31)+1))

    const float4* xi = (const float4*)(x   + (long)row * TT) + lane;
    f32x4*        oi = (f32x4*)      (out + (long)row * TT) + lane;

    // Issue ALL loads first (warmup + 4 main batches), then compute.
    float4 vw = make_float4(0.f, 0.f, 0.f, 0.f);
    if (seg != 0) vw = xi[(base - 1) * 64];

    float4 vbuf[ITERS];
    #pragma unroll
    for (int j = 0; j < ITERS; ++j) {
        const int it = base + j;
        const bool act = (it < NFULL) | (lane < TAILL);
        float4 r = make_float4(0.f, 0.f, 0.f, 0.f);
        if (act) r = xi[it * 64];
        vbuf[j] = r;
    }

    // Warmup: one scan over the previous batch to rebuild incoming state.
    float carry = 0.0f;
    if (seg != 0) {
        float b = vw.x;
        b = fmaf(A, b, vw.y);
        b = fmaf(A, b, vw.z);
        float B = fmaf(A, b, vw.w);
        B = fmaf(A4,  DPPF(B, 0x111, 0xf), B);
        B = fmaf(A8,  DPPF(B, 0x112, 0xf), B);
        B = fmaf(A16, DPPF(B, 0x114, 0xf), B);
        B = fmaf(A32, DPPF(B, 0x118, 0xf), B);
        B = fmaf(w15, DPPF(B, 0x142, 0xa), B);
        B = fmaf(w31, DPPF(B, 0x143, 0xc), B);
        carry = __int_as_float(__builtin_amdgcn_readlane(__float_as_int(B), 63));
    }

    #pragma unroll
    for (int j = 0; j < ITERS; ++j) {
        const int it = base + j;
        const bool act = (it < NFULL) | (lane < TAILL);
        float4 v = vbuf[j];

        // Lane-local aggregate from 0 (n-space).
        float b = v.x;
        b = fmaf(A, b, v.y);
        b = fmaf(A, b, v.z);
        float B0 = fmaf(A, b, v.w);
        float B = B0;

        // Weighted inclusive wave scan, all-DPP.
        B = fmaf(A4,  DPPF(B, 0x111, 0xf), B);   // row_shr:1
        B = fmaf(A8,  DPPF(B, 0x112, 0xf), B);   // row_shr:2
        B = fmaf(A16, DPPF(B, 0x114, 0xf), B);   // row_shr:4
        B = fmaf(A32, DPPF(B, 0x118, 0xf), B);   // row_shr:8
        B = fmaf(w15, DPPF(B, 0x142, 0xa), B);   // row_bcast15 -> rows 1,3
        B = fmaf(w31, DPPF(B, 0x143, 0xc), B);   // row_bcast31 -> rows 2,3

        // Exclusive (previous-lane inclusive) without a shuffle.
        float bp = (B - B0) * INVA4;

        // n-state entering this lane's 4 elements.
        float n = fmaf(powAl, carry, bp);

        // Carry for next batch via readlane (SGPR broadcast).
        float b63 = __int_as_float(__builtin_amdgcn_readlane(__float_as_int(B), 63));
        carry = fmaf(A256, carry, b63);

        // Per-element recompute + PCEN nonlinearity (single-inst trans).
        f32x4 o;
        n = fmaf(A, n, v.x);
        o.x = __builtin_amdgcn_sqrtf(fmaf(v.x, __builtin_amdgcn_exp2f(NA * __builtin_amdgcn_logf(fmaf(S, n, EPS))), 2.0f)) - SQRT2;
        n = fmaf(A, n, v.y);
        o.y = __builtin_amdgcn_sqrtf(fmaf(v.y, __builtin_amdgcn_exp2f(NA * __builtin_amdgcn_logf(fmaf(S, n, EPS))), 2.0f)) - SQRT2;
        n = fmaf(A, n, v.z);
        o.z = __builtin_amdgcn_sqrtf(fmaf(v.z, __builtin_amdgcn_exp2f(NA * __builtin_amdgcn_logf(fmaf(S, n, EPS))), 2.0f)) - SQRT2;
        n = fmaf(A, n, v.w);
        o.w = __builtin_amdgcn_sqrtf(fmaf(v.w, __builtin_amdgcn_exp2f(NA * __builtin_amdgcn_logf(fmaf(S, n, EPS))), 2.0f)) - SQRT2;

        if (act) __builtin_nontemporal_store(o, &oi[it * 64]);
    }
}

extern "C" void kernel_launch(void* const* d_in, const int* in_sizes, int n_in,
                              void* d_out, int out_size, void* d_ws, size_t ws_size,
                              hipStream_t stream) {
    const float* x = (const float*)d_in[0];
    float* out = (float*)d_out;
    const int block = 256;
    const int grid = (NROWS * SEGS * 64) / block;  // 32768 waves = 8192 blocks
    pcen_kernel<<<grid, block, 0, stream>>>(x, out);
}